// Round 1
// baseline (154.365 us; speedup 1.0000x reference)
//
#include <hip/hip_runtime.h>
#include <hip/hip_bf16.h>

#define T_TOK 8192
#define KDIM  1024
#define NDIM  1024
#define NEXP  8
#define LDA   40   // LDS row stride in bf16 elems (80 B = 16B-aligned, bank-friendly)

typedef __bf16 bf16x8 __attribute__((ext_vector_type(8)));
typedef __bf16 bf16x4 __attribute__((ext_vector_type(4)));
typedef float  f32x4  __attribute__((ext_vector_type(4)));

__global__ __launch_bounds__(256) void moe_gemm_kernel(
    const float* __restrict__ x, const int* __restrict__ gs,
    const float* __restrict__ W, const float* __restrict__ bias,
    float* __restrict__ out)
{
  __shared__ __bf16 Al[128 * LDA];
  __shared__ __bf16 Bl[128 * LDA];

  const int e  = blockIdx.z;
  const int mt = blockIdx.y;
  const int nt = blockIdx.x;

  // prefix sum of the 8 group sizes (tiny, L1/L2-resident)
  int off = 0;
#pragma unroll
  for (int i = 0; i < NEXP; ++i) { int g = gs[i]; if (i < e) off += g; }
  const int ge = gs[e];
  const int m0 = mt * 128;
  if (m0 >= ge) return;                 // block-uniform early exit
  const int rows = min(128, ge - m0);
  const int row0 = off + m0;
  const int n0   = nt * 128;

  const int t    = threadIdx.x;
  const int lane = t & 63;
  const int wv   = t >> 6;
  const int wm   = wv & 1;
  const int wn   = wv >> 1;
  const int lm   = lane & 15;
  const int lg   = lane >> 4;

  // staging indices
  const int am = t >> 3;    // A: base row (0..31); rows am+32p
  const int kq = t & 7;     // A: float4 slot within 32-wide k
  const int nb = t & 127;   // B: column within tile
  const int kh = t >> 7;    // B: k half (0/1)

  float4 aReg[4];
  float  bReg[16];

  const float* Wp = W + (size_t)e * KDIM * NDIM + n0 + nb;

  auto load_tile = [&](int kt) {
#pragma unroll
    for (int p = 0; p < 4; ++p) {
      int r = am + 32 * p;
      if (r < rows) {
        aReg[p] = *(const float4*)(x + (size_t)(row0 + r) * KDIM + kt * 32 + kq * 4);
      } else {
        aReg[p] = make_float4(0.f, 0.f, 0.f, 0.f);   // zero-pad ragged tail
      }
    }
    const float* wp = Wp + (size_t)(kt * 32 + kh * 16) * NDIM;
#pragma unroll
    for (int j = 0; j < 16; ++j) bReg[j] = wp[(size_t)j * NDIM];
  };

  auto store_tile = [&]() {
#pragma unroll
    for (int p = 0; p < 4; ++p) {
      bf16x4 v;
      v[0] = (__bf16)aReg[p].x; v[1] = (__bf16)aReg[p].y;
      v[2] = (__bf16)aReg[p].z; v[3] = (__bf16)aReg[p].w;
      *(bf16x4*)(Al + (am + 32 * p) * LDA + kq * 4) = v;
    }
    bf16x8 b0, b1;
#pragma unroll
    for (int j = 0; j < 8; ++j) { b0[j] = (__bf16)bReg[j]; b1[j] = (__bf16)bReg[8 + j]; }
    *(bf16x8*)(Bl + nb * LDA + kh * 16)     = b0;
    *(bf16x8*)(Bl + nb * LDA + kh * 16 + 8) = b1;
  };

  f32x4 acc[4][4] = {};

  load_tile(0);
#pragma unroll 1
  for (int kt = 0; kt < KDIM / 32; ++kt) {
    __syncthreads();
    store_tile();
    __syncthreads();
    if (kt + 1 < KDIM / 32) load_tile(kt + 1);   // register prefetch overlaps MFMAs

    bf16x8 af[4], bf[4];
#pragma unroll
    for (int i = 0; i < 4; ++i)
      af[i] = *(const bf16x8*)(Al + (wm * 64 + i * 16 + lm) * LDA + lg * 8);
#pragma unroll
    for (int j = 0; j < 4; ++j)
      bf[j] = *(const bf16x8*)(Bl + (wn * 64 + j * 16 + lm) * LDA + lg * 8);

#pragma unroll
    for (int i = 0; i < 4; ++i)
#pragma unroll
      for (int j = 0; j < 4; ++j)
        acc[i][j] = __builtin_amdgcn_mfma_f32_16x16x32_bf16(af[i], bf[j], acc[i][j], 0, 0, 0);
  }

  // epilogue: bias add + guarded fp32 store
  float bj[4];
#pragma unroll
  for (int j = 0; j < 4; ++j) bj[j] = bias[e * NDIM + n0 + wn * 64 + j * 16 + lm];

  float* op = out + (size_t)row0 * NDIM + n0;
#pragma unroll
  for (int i = 0; i < 4; ++i) {
#pragma unroll
    for (int r = 0; r < 4; ++r) {
      int rr = wm * 64 + i * 16 + lg * 4 + r;   // C/D: row = quad*4 + reg, col = lane&15
      if (rr < rows) {
#pragma unroll
        for (int j = 0; j < 4; ++j)
          op[(size_t)rr * NDIM + wn * 64 + j * 16 + lm] = acc[i][j][r] + bj[j];
      }
    }
  }
}

extern "C" void kernel_launch(void* const* d_in, const int* in_sizes, int n_in,
                              void* d_out, int out_size, void* d_ws, size_t ws_size,
                              hipStream_t stream) {
  const float* x    = (const float*)d_in[0];
  const int*   gs   = (const int*)d_in[1];
  const float* W    = (const float*)d_in[2];
  const float* bias = (const float*)d_in[3];
  float*       out  = (float*)d_out;

  dim3 grid(NDIM / 128, T_TOK / 128, NEXP);   // (n-tiles, worst-case m-tiles, experts)
  moe_gemm_kernel<<<grid, 256, 0, stream>>>(x, gs, W, bias, out);
}